// Round 1
// baseline (1066.324 us; speedup 1.0000x reference)
//
#include <hip/hip_runtime.h>
#include <hip/hip_bf16.h>

typedef float f32x4 __attribute__((ext_vector_type(4)));
typedef short bf16x8 __attribute__((ext_vector_type(8)));

#define DI __device__ __forceinline__

DI unsigned short f2b(float f) {
  unsigned u = __float_as_uint(f);
  return (unsigned short)((u + 0x7fffu + ((u >> 16) & 1u)) >> 16);
}
DI float b2f(unsigned short h) { return __uint_as_float(((unsigned)h) << 16); }
DI float softplus_f(float z) { return fmaxf(z, 0.f) + __logf(1.f + __expf(-fabsf(z))); }

// ---------------------------------------------------------------------------
// K0: prep — bf16 MFMA-fragment re-layouts of w1/w2/ww, row-sums of wb/bb, A2=A@A
// Fragment layout for B-operand of mfma_f32_16x16x32_bf16:
//   lane holds B[k = q*8+j][n = lane&15], j contiguous -> store [kgroup][n][8]
// ---------------------------------------------------------------------------
__global__ void k_prep(const float* __restrict__ w1, const float* __restrict__ w2,
                       const float* __restrict__ ww, const float* __restrict__ wb,
                       const float* __restrict__ bb, const float* __restrict__ A,
                       unsigned short* __restrict__ W1F, unsigned short* __restrict__ W2F,
                       unsigned short* __restrict__ WWF, float* __restrict__ A2,
                       float* __restrict__ WBS, float* __restrict__ BBS)
{
  __shared__ float rowL[256];
  const int blk = blockIdx.x, tid = threadIdx.x;
  if (blk < 128) {                    // W1F: [kg=k/8 (128)][n=u*128+f (256)][j (8)]
    int t = blk * 256 + tid;
    int u = t >> 14, kg = (t >> 7) & 127, f = t & 127;
    const float* src = w1 + u * 131072 + kg * 8 * 128 + f;   // stride 128 over j
    uint4 pv;
    pv.x = (unsigned)f2b(src[0])       | ((unsigned)f2b(src[128])   << 16);
    pv.y = (unsigned)f2b(src[2 * 128]) | ((unsigned)f2b(src[3 * 128]) << 16);
    pv.z = (unsigned)f2b(src[4 * 128]) | ((unsigned)f2b(src[5 * 128]) << 16);
    pv.w = (unsigned)f2b(src[6 * 128]) | ((unsigned)f2b(src[7 * 128]) << 16);
    *(uint4*)&W1F[(unsigned)(((kg << 8) + (u << 7) + f) << 3)] = pv;
  } else if (blk < 192) {             // WWF: [u][kg=g/8 (8)][i (1024)][j]
    int t = (blk - 128) * 256 + tid;
    int u = t >> 13, kg = (t >> 10) & 7, i = t & 1023;
    const float* src = ww + u * 65536 + kg * 8 * 1024 + i;   // stride 1024 over j
    uint4 pv;
    pv.x = (unsigned)f2b(src[0])        | ((unsigned)f2b(src[1024])     << 16);
    pv.y = (unsigned)f2b(src[2 * 1024]) | ((unsigned)f2b(src[3 * 1024]) << 16);
    pv.z = (unsigned)f2b(src[4 * 1024]) | ((unsigned)f2b(src[5 * 1024]) << 16);
    pv.w = (unsigned)f2b(src[6 * 1024]) | ((unsigned)f2b(src[7 * 1024]) << 16);
    *(uint4*)&WWF[(unsigned)((((u * 8 + kg) << 10) + i) << 3)] = pv;
  } else if (blk < 200) {             // W2F: [u][kg=f/8 (16)][g (64)][j]
    int t = (blk - 192) * 256 + tid;
    int u = t >> 10, kg = (t >> 6) & 15, g = t & 63;
    const float* src = w2 + u * 8192 + kg * 8 * 64 + g;      // stride 64 over j
    uint4 pv;
    pv.x = (unsigned)f2b(src[0])      | ((unsigned)f2b(src[64])     << 16);
    pv.y = (unsigned)f2b(src[2 * 64]) | ((unsigned)f2b(src[3 * 64]) << 16);
    pv.z = (unsigned)f2b(src[4 * 64]) | ((unsigned)f2b(src[5 * 64]) << 16);
    pv.w = (unsigned)f2b(src[6 * 64]) | ((unsigned)f2b(src[7 * 64]) << 16);
    *(uint4*)&W2F[(unsigned)((((u * 16 + kg) << 6) + g) << 3)] = pv;
  } else if (blk < 456) {             // A2 row r (fp32 exact)
    int r = blk - 200;
    rowL[tid] = A[r * 256 + tid];
    __syncthreads();
    float acc0 = 0.f, acc1 = 0.f;
    #pragma unroll 8
    for (int k = 0; k < 256; k += 2) {
      acc0 += rowL[k] * A[k * 256 + tid];
      acc1 += rowL[k + 1] * A[(k + 1) * 256 + tid];
    }
    A2[r * 256 + tid] = acc0 + acc1;
  } else if (blk < 488) {             // WBS[u*64+g] = sum_i wb[u][g][i]
    int rowid = (blk - 456) * 4 + (tid >> 6);
    int lane = tid & 63;
    const f32x4* src = (const f32x4*)(wb + (size_t)rowid * 1024);
    float s = 0.f;
    #pragma unroll
    for (int rr = 0; rr < 4; ++rr) {
      f32x4 v = src[lane + 64 * rr];
      s += (v[0] + v[1]) + (v[2] + v[3]);
    }
    #pragma unroll
    for (int m = 1; m < 64; m <<= 1) s += __shfl_xor(s, m);
    if (lane == 0) WBS[rowid] = s;
  } else {                            // BBS[u] = sum_i bb[u][i]
    int wv = tid >> 6, lane = tid & 63;
    if (wv < 2) {
      const f32x4* src = (const f32x4*)(bb + wv * 1024);
      float s = 0.f;
      #pragma unroll
      for (int rr = 0; rr < 4; ++rr) {
        f32x4 v = src[lane + 64 * rr];
        s += (v[0] + v[1]) + (v[2] + v[3]);
      }
      #pragma unroll
      for (int m = 1; m < 64; m <<= 1) s += __shfl_xor(s, m);
      if (lane == 0) BBS[wv] = s;
    }
  }
}

// ---------------------------------------------------------------------------
// K1: chain — c_j = A^j c0, parity-2 via A2; inline W[127-j] = B_ssm @ c_j
// block par in {0,1}: owns j = par, par+2, ..., par+126 (64 vectors)
// A2 row of this thread lives in 256 VGPRs; B_ssm quarter-slice in 64 VGPRs.
// ---------------------------------------------------------------------------
__global__ __launch_bounds__(256, 1) void k_chain(
    const float* __restrict__ A, const float* __restrict__ A2,
    const float* __restrict__ Bs, const float* __restrict__ Cs, float* __restrict__ Wmat)
{
  __shared__ float cb[2][256];
  __shared__ float wpart[64][4][64];
  const int tid = threadIdx.x;
  const int lane = tid & 63, q4 = tid >> 6;   // q4 = wave id = quarter of s-range
  const int par = blockIdx.x;

  float bq[64];                                // Bs[m=lane][s = q4*64 + 0..63]
  {
    const f32x4* bsrc = (const f32x4*)(Bs + lane * 256 + q4 * 64);
    #pragma unroll
    for (int s4 = 0; s4 < 16; ++s4) {
      f32x4 v = bsrc[s4];
      bq[4 * s4] = v[0]; bq[4 * s4 + 1] = v[1]; bq[4 * s4 + 2] = v[2]; bq[4 * s4 + 3] = v[3];
    }
  }
  if (par == 0) cb[0][tid] = Cs[tid];
  else          cb[1][tid] = Cs[tid];
  __syncthreads();
  if (par == 1) {                              // seed c1 = A @ c0
    const f32x4* ar = (const f32x4*)(A + tid * 256);
    float s0 = 0.f, s1 = 0.f, s2 = 0.f, s3 = 0.f;
    #pragma unroll
    for (int s4 = 0; s4 < 64; ++s4) {
      f32x4 av = ar[s4];
      f32x4 cv = ((const f32x4*)cb[1])[s4];
      s0 += av[0] * cv[0]; s1 += av[1] * cv[1]; s2 += av[2] * cv[2]; s3 += av[3] * cv[3];
    }
    cb[0][tid] = (s0 + s1) + (s2 + s3);
    __syncthreads();
  }
  float a2r[256];
  {
    const f32x4* a2src = (const f32x4*)(A2 + tid * 256);
    #pragma unroll
    for (int s4 = 0; s4 < 64; ++s4) {
      f32x4 v = a2src[s4];
      a2r[4 * s4] = v[0]; a2r[4 * s4 + 1] = v[1]; a2r[4 * s4 + 2] = v[2]; a2r[4 * s4 + 3] = v[3];
    }
  }
  int p = 0;
  for (int it = 0; it < 64; ++it) {
    const float* c = cb[p];
    float wa = 0.f;                            // W-partial: my quarter of B row `lane`
    #pragma unroll
    for (int s4 = 0; s4 < 16; ++s4) {
      f32x4 cv = ((const f32x4*)c)[q4 * 16 + s4];
      wa += bq[4 * s4] * cv[0] + bq[4 * s4 + 1] * cv[1] + bq[4 * s4 + 2] * cv[2] + bq[4 * s4 + 3] * cv[3];
    }
    wpart[it][q4][lane] = wa;
    if (it == 63) break;
    float x0 = 0.f, x1 = 0.f, x2 = 0.f, x3 = 0.f;   // c_next = A2 @ c
    #pragma unroll
    for (int s4 = 0; s4 < 64; ++s4) {
      f32x4 cv = ((const f32x4*)c)[s4];
      x0 += a2r[4 * s4] * cv[0]; x1 += a2r[4 * s4 + 1] * cv[1];
      x2 += a2r[4 * s4 + 2] * cv[2]; x3 += a2r[4 * s4 + 3] * cv[3];
    }
    cb[p ^ 1][tid] = (x0 + x1) + (x2 + x3);
    p ^= 1;
    __syncthreads();
  }
  __syncthreads();
  for (int o = tid; o < 4096; o += 256) {      // reduce 4 quarters, write W rows
    int it = o >> 6, m = o & 63;
    int trow = 127 - (par + 2 * it);
    Wmat[trow * 64 + m] =
        (wpart[it][0][m] + wpart[it][1][m]) + (wpart[it][2][m] + wpart[it][3][m]);
  }
}

// ---------------------------------------------------------------------------
// K2: KAN inner path — per 64-row block: x tile resident in LDS (bf16),
// L1 (K=1024) -> relu -> L2 (K=128) -> relu -> gen (K=64, N=1024) + softplus*x
// MFMA 16x16x32 bf16 throughout; weights pre-laid-out as B-fragments (global/L2).
// Writes inner[b][u] (fp32) to workspace.
// ---------------------------------------------------------------------------
__global__ __launch_bounds__(256, 1) void k_kan(
    const float* __restrict__ x, const unsigned short* __restrict__ W1F,
    const unsigned short* __restrict__ W2F, const unsigned short* __restrict__ WWF,
    const float* __restrict__ b1, const float* __restrict__ b2, const float* __restrict__ bwp,
    const float* __restrict__ WBS, const float* __restrict__ BBS, float* __restrict__ INNER)
{
  __shared__ unsigned short XA[64 * 1032];        // x tile bf16, row stride 1032 (16B-aligned, 4-bank shift)
  __shared__ unsigned short H1s[4][16 * 136];     // per-wave h1 round-trip
  __shared__ unsigned short H2s[4][16 * 72];      // per-wave h2 round-trip (per u)
  const int tid = threadIdx.x;
  const int wave = tid >> 6, lane = tid & 63, n16 = lane & 15, q = lane >> 4;
  const int row0 = blockIdx.x * 64;
  const int srow = tid >> 2, sc4 = tid & 3;
  const float* xrow = x + (size_t)(row0 + srow) * 1024;

  f32x4 pf[8];
  {                                              // stage chunk 0
    const f32x4* s = (const f32x4*)xrow + sc4;
    #pragma unroll
    for (int r = 0; r < 8; ++r) pf[r] = s[4 * r];
    #pragma unroll
    for (int r = 0; r < 8; ++r) {
      uint2 pk;
      pk.x = (unsigned)f2b(pf[r][0]) | ((unsigned)f2b(pf[r][1]) << 16);
      pk.y = (unsigned)f2b(pf[r][2]) | ((unsigned)f2b(pf[r][3]) << 16);
      *(uint2*)&XA[srow * 1032 + (sc4 + 4 * r) * 4] = pk;
    }
  }
  __syncthreads();

  #pragma unroll 1
  for (int u = 0; u < 2; ++u) {
    f32x4 acc[8];
    #pragma unroll
    for (int i = 0; i < 8; ++i) acc[i] = (f32x4){0.f, 0.f, 0.f, 0.f};

    #pragma unroll 1
    for (int kc = 0; kc < 8; ++kc) {
      if (u == 0 && kc < 7) {                    // prefetch next chunk (issue early)
        const f32x4* s = (const f32x4*)xrow + (kc + 1) * 32 + sc4;
        #pragma unroll
        for (int r = 0; r < 8; ++r) pf[r] = s[4 * r];
      }
      #pragma unroll
      for (int ks = 0; ks < 4; ++ks) {
        bf16x8 af = *(const bf16x8*)&XA[(wave * 16 + n16) * 1032 + kc * 128 + ks * 32 + q * 8];
        #pragma unroll
        for (int nt = 0; nt < 8; ++nt) {
          int kg = kc * 16 + ks * 4 + q;
          bf16x8 bfr = *(const bf16x8*)&W1F[(unsigned)((kg * 256 + u * 128 + nt * 16 + n16) * 8)];
          acc[nt] = __builtin_amdgcn_mfma_f32_16x16x32_bf16(af, bfr, acc[nt], 0, 0, 0);
        }
      }
      if (u == 0 && kc < 7) {                    // commit next chunk to LDS
        #pragma unroll
        for (int r = 0; r < 8; ++r) {
          uint2 pk;
          pk.x = (unsigned)f2b(pf[r][0]) | ((unsigned)f2b(pf[r][1]) << 16);
          pk.y = (unsigned)f2b(pf[r][2]) | ((unsigned)f2b(pf[r][3]) << 16);
          *(uint2*)&XA[srow * 1032 + (kc + 1) * 128 + (sc4 + 4 * r) * 4] = pk;
        }
      }
      if (u == 0) __syncthreads();
    }

    // L1 epilogue: h1 = relu(acc + b1) -> H1s (bf16)
    #pragma unroll
    for (int nt = 0; nt < 8; ++nt) {
      float bias = b1[u * 128 + nt * 16 + n16];
      #pragma unroll
      for (int r = 0; r < 4; ++r) {
        float h = fmaxf(acc[nt][r] + bias, 0.f);
        H1s[wave][(q * 4 + r) * 136 + nt * 16 + n16] = f2b(h);
      }
    }
    // L2: h2 = relu(h1 @ w2 + b2), K=128, N=64
    f32x4 acc2[4];
    #pragma unroll
    for (int i = 0; i < 4; ++i) acc2[i] = (f32x4){0.f, 0.f, 0.f, 0.f};
    #pragma unroll
    for (int ks = 0; ks < 4; ++ks) {
      bf16x8 af = *(const bf16x8*)&H1s[wave][n16 * 136 + ks * 32 + q * 8];
      #pragma unroll
      for (int nt = 0; nt < 4; ++nt) {
        bf16x8 bfr = *(const bf16x8*)&W2F[(unsigned)(((u * 16 + ks * 4 + q) * 64 + nt * 16 + n16) * 8)];
        acc2[nt] = __builtin_amdgcn_mfma_f32_16x16x32_bf16(af, bfr, acc2[nt], 0, 0, 0);
      }
    }
    float bsum[4] = {0.f, 0.f, 0.f, 0.f};
    #pragma unroll
    for (int nt = 0; nt < 4; ++nt) {
      float bias = b2[u * 64 + nt * 16 + n16];
      float wv = WBS[u * 64 + nt * 16 + n16];
      #pragma unroll
      for (int r = 0; r < 4; ++r) {
        float h = fmaxf(acc2[nt][r] + bias, 0.f);
        H2s[wave][(q * 4 + r) * 72 + nt * 16 + n16] = f2b(h);
        bsum[r] += h * wv;                       // bias-generator term: h2 . wbs
      }
    }
    // gen: z = h2 @ ww + bw ; inner_w = sum_i softplus(z_i) * x_i
    bf16x8 g0 = *(const bf16x8*)&H2s[wave][n16 * 72 + q * 8];
    bf16x8 g1 = *(const bf16x8*)&H2s[wave][n16 * 72 + 32 + q * 8];
    float wsum[4] = {0.f, 0.f, 0.f, 0.f};
    #pragma unroll 4
    for (int nt = 0; nt < 64; ++nt) {
      int i = nt * 16 + n16;
      bf16x8 w0 = *(const bf16x8*)&WWF[(unsigned)(((u * 8 + q) * 1024 + i) * 8)];
      bf16x8 w1v = *(const bf16x8*)&WWF[(unsigned)(((u * 8 + 4 + q) * 1024 + i) * 8)];
      f32x4 z = (f32x4){0.f, 0.f, 0.f, 0.f};
      z = __builtin_amdgcn_mfma_f32_16x16x32_bf16(g0, w0, z, 0, 0, 0);
      z = __builtin_amdgcn_mfma_f32_16x16x32_bf16(g1, w1v, z, 0, 0, 0);
      float bwv = bwp[u * 1024 + i];
      #pragma unroll
      for (int r = 0; r < 4; ++r) {
        float zz = z[r] + bwv;
        float s = softplus_f(zz);
        float xv = b2f(XA[(wave * 16 + q * 4 + r) * 1032 + i]);
        wsum[r] += s * xv;
      }
    }
    // reduce over the 16 lanes holding the same rows; write inner[b][u]
    #pragma unroll
    for (int r = 0; r < 4; ++r) {
      float v = wsum[r] + bsum[r];
      v += __shfl_xor(v, 1); v += __shfl_xor(v, 2);
      v += __shfl_xor(v, 4); v += __shfl_xor(v, 8);
      if (n16 == 0) INNER[(size_t)(row0 + wave * 16 + q * 4 + r) * 2 + u] = v + BBS[u];
    }
  }
}

// ---------------------------------------------------------------------------
// K3: mamba dot (streaming, HBM-bound) + outer generator MLP + combine
// one wave per row; W (128x64 fp32) staged in LDS per block
// ---------------------------------------------------------------------------
__global__ __launch_bounds__(256, 4) void k_mamba(
    const float* __restrict__ xm, const float* __restrict__ Wmat, const float* __restrict__ INNER,
    const float* __restrict__ ow1, const float* __restrict__ ob1,
    const float* __restrict__ ow2, const float* __restrict__ ob2,
    const float* __restrict__ oww, const float* __restrict__ obw,
    const float* __restrict__ owb, const float* __restrict__ obb,
    const float* __restrict__ wkan, const float* __restrict__ wmamba, float* __restrict__ out)
{
  __shared__ float Ws[8192];
  __shared__ float h1o[4][256];
  __shared__ float h2o[4][128];
  const int tid = threadIdx.x, wave = tid >> 6, lane = tid & 63;
  #pragma unroll
  for (int i = 0; i < 8; ++i) ((f32x4*)Ws)[i * 256 + tid] = ((const f32x4*)Wmat)[i * 256 + tid];
  __syncthreads();
  const int row = blockIdx.x * 4 + wave;
  const float* xr = xm + (size_t)row * 8192;
  float a0 = 0.f, a1 = 0.f, a2 = 0.f, a3 = 0.f;
  #pragma unroll 8
  for (int i = 0; i < 32; ++i) {
    f32x4 xv = ((const f32x4*)xr)[i * 64 + lane];
    f32x4 wv = ((const f32x4*)Ws)[i * 64 + lane];
    a0 += xv[0] * wv[0]; a1 += xv[1] * wv[1]; a2 += xv[2] * wv[2]; a3 += xv[3] * wv[3];
  }
  float dot = (a0 + a1) + (a2 + a3);
  #pragma unroll
  for (int m = 1; m < 64; m <<= 1) dot += __shfl_xor(dot, m);

  // ---- outer generator (fp32 VALU, hidden under HBM) ----
  float i0 = INNER[(size_t)row * 2], i1 = INNER[(size_t)row * 2 + 1];
  #pragma unroll
  for (int of = 0; of < 4; ++of) {
    int idx = of * 64 + lane;                   // (o = idx>>7, f = idx&127)
    int o = idx >> 7, f = idx & 127;
    float h = fmaxf(i0 * ow1[o * 256 + f] + i1 * ow1[o * 256 + 128 + f] + ob1[idx], 0.f);
    h1o[wave][idx] = h;
  }
  __syncthreads();
  #pragma unroll
  for (int oh = 0; oh < 2; ++oh) {              // h2o[o=oh][g=lane]
    float acc = ob2[oh * 64 + lane];
    #pragma unroll 8
    for (int f = 0; f < 128; ++f)
      acc += h1o[wave][oh * 128 + f] * ow2[(oh * 128 + f) * 64 + lane];
    h2o[wave][oh * 64 + lane] = fmaxf(acc, 0.f);
  }
  __syncthreads();
  float p0 = h2o[wave][lane] * oww[lane];
  float p1 = h2o[wave][64 + lane] * oww[64 + lane];
  float pb0 = h2o[wave][lane] * owb[lane];
  float pb1 = h2o[wave][64 + lane] * owb[64 + lane];
  #pragma unroll
  for (int m = 1; m < 64; m <<= 1) {
    p0 += __shfl_xor(p0, m); p1 += __shfl_xor(p1, m);
    pb0 += __shfl_xor(pb0, m); pb1 += __shfl_xor(pb1, m);
  }
  float w0 = softplus_f(p0 + obw[0]), w1 = softplus_f(p1 + obw[1]);
  float b0 = pb0 + obb[0], b1v = pb1 + obb[1];
  float isum = i0 + i1;
  float kan = w0 * isum + 2.f * b0 + w1 * isum + 2.f * b1v;
  if (lane == 0) out[row] = wkan[0] * kan + wmamba[0] * dot;
}

// ---------------------------------------------------------------------------
extern "C" void kernel_launch(void* const* d_in, const int* in_sizes, int n_in,
                              void* d_out, int out_size, void* d_ws, size_t ws_size,
                              hipStream_t stream) {
  (void)in_sizes; (void)n_in; (void)out_size; (void)ws_size;
  const float* x_kan   = (const float*)d_in[0];
  const float* x_mamba = (const float*)d_in[1];
  const float* in_w1 = (const float*)d_in[2];
  const float* in_b1 = (const float*)d_in[3];
  const float* in_w2 = (const float*)d_in[4];
  const float* in_b2 = (const float*)d_in[5];
  const float* in_ww = (const float*)d_in[6];
  const float* in_bw = (const float*)d_in[7];
  const float* in_wb = (const float*)d_in[8];
  const float* in_bb = (const float*)d_in[9];
  const float* out_w1 = (const float*)d_in[10];
  const float* out_b1 = (const float*)d_in[11];
  const float* out_w2 = (const float*)d_in[12];
  const float* out_b2 = (const float*)d_in[13];
  const float* out_ww = (const float*)d_in[14];
  const float* out_bw = (const float*)d_in[15];
  const float* out_wb = (const float*)d_in[16];
  const float* out_bb = (const float*)d_in[17];
  const float* A  = (const float*)d_in[18];
  const float* Bs = (const float*)d_in[19];
  const float* Cs = (const float*)d_in[20];
  const float* wkan   = (const float*)d_in[21];
  const float* wmamba = (const float*)d_in[22];
  float* out = (float*)d_out;

  char* ws = (char*)d_ws;
  unsigned short* W1F = (unsigned short*)(ws + 0);         // 512 KB
  unsigned short* WWF = (unsigned short*)(ws + 524288);    // 256 KB
  unsigned short* W2F = (unsigned short*)(ws + 786432);    // 32 KB
  float* A2    = (float*)(ws + 819200);                    // 256 KB
  float* WBS   = (float*)(ws + 1081344);                   // 512 B
  float* BBS   = (float*)(ws + 1082368);                   // 8 B
  float* WMAT  = (float*)(ws + 1082624);                   // 32 KB
  float* INNER = (float*)(ws + 1115392);                   // 128 KB  (total ~1.19 MB)

  k_prep<<<489, 256, 0, stream>>>(in_w1, in_w2, in_ww, in_wb, in_bb, A,
                                  W1F, W2F, WWF, A2, WBS, BBS);
  k_chain<<<2, 256, 0, stream>>>(A, A2, Bs, Cs, WMAT);
  k_kan<<<256, 256, 0, stream>>>(x_kan, W1F, W2F, WWF, in_b1, in_b2, in_bw,
                                 WBS, BBS, INNER);
  k_mamba<<<4096, 256, 0, stream>>>(x_mamba, WMAT, INNER, out_w1, out_b1, out_w2, out_b2,
                                    out_ww, out_bw, out_wb, out_bb, wkan, wmamba, out);
}

// Round 2
// 905.755 us; speedup vs baseline: 1.1773x; 1.1773x over previous
//
#include <hip/hip_runtime.h>
#include <hip/hip_bf16.h>

typedef float f32x4 __attribute__((ext_vector_type(4)));
typedef short bf16x8 __attribute__((ext_vector_type(8)));

#define DI __device__ __forceinline__

DI unsigned short f2b(float f) {
  unsigned u = __float_as_uint(f);
  return (unsigned short)((u + 0x7fffu + ((u >> 16) & 1u)) >> 16);
}
DI float b2f(unsigned short h) { return __uint_as_float(((unsigned)h) << 16); }
DI float softplus_f(float z) { return fmaxf(z, 0.f) + __logf(1.f + __expf(-fabsf(z))); }

// ---------------------------------------------------------------------------
// K0: prep — bf16 MFMA-fragment re-layouts of w1/w2/ww, row-sums of wb/bb, A2=A@A
// ---------------------------------------------------------------------------
__global__ void k_prep(const float* __restrict__ w1, const float* __restrict__ w2,
                       const float* __restrict__ ww, const float* __restrict__ wb,
                       const float* __restrict__ bb, const float* __restrict__ A,
                       unsigned short* __restrict__ W1F, unsigned short* __restrict__ W2F,
                       unsigned short* __restrict__ WWF, float* __restrict__ A2,
                       float* __restrict__ WBS, float* __restrict__ BBS)
{
  __shared__ float rowL[256];
  const int blk = blockIdx.x, tid = threadIdx.x;
  if (blk < 128) {                    // W1F: [kg=k/8 (128)][n=u*128+f (256)][j (8)]
    int t = blk * 256 + tid;
    int u = t >> 14, kg = (t >> 7) & 127, f = t & 127;
    const float* src = w1 + u * 131072 + kg * 8 * 128 + f;
    uint4 pv;
    pv.x = (unsigned)f2b(src[0])       | ((unsigned)f2b(src[128])   << 16);
    pv.y = (unsigned)f2b(src[2 * 128]) | ((unsigned)f2b(src[3 * 128]) << 16);
    pv.z = (unsigned)f2b(src[4 * 128]) | ((unsigned)f2b(src[5 * 128]) << 16);
    pv.w = (unsigned)f2b(src[6 * 128]) | ((unsigned)f2b(src[7 * 128]) << 16);
    *(uint4*)&W1F[(unsigned)(((kg << 8) + (u << 7) + f) << 3)] = pv;
  } else if (blk < 192) {             // WWF: [u][kg=g/8 (8)][i (1024)][j]
    int t = (blk - 128) * 256 + tid;
    int u = t >> 13, kg = (t >> 10) & 7, i = t & 1023;
    const float* src = ww + u * 65536 + kg * 8 * 1024 + i;
    uint4 pv;
    pv.x = (unsigned)f2b(src[0])        | ((unsigned)f2b(src[1024])     << 16);
    pv.y = (unsigned)f2b(src[2 * 1024]) | ((unsigned)f2b(src[3 * 1024]) << 16);
    pv.z = (unsigned)f2b(src[4 * 1024]) | ((unsigned)f2b(src[5 * 1024]) << 16);
    pv.w = (unsigned)f2b(src[6 * 1024]) | ((unsigned)f2b(src[7 * 1024]) << 16);
    *(uint4*)&WWF[(unsigned)((((u * 8 + kg) << 10) + i) << 3)] = pv;
  } else if (blk < 200) {             // W2F: [u][kg=f/8 (16)][g (64)][j]
    int t = (blk - 192) * 256 + tid;
    int u = t >> 10, kg = (t >> 6) & 15, g = t & 63;
    const float* src = w2 + u * 8192 + kg * 8 * 64 + g;
    uint4 pv;
    pv.x = (unsigned)f2b(src[0])      | ((unsigned)f2b(src[64])     << 16);
    pv.y = (unsigned)f2b(src[2 * 64]) | ((unsigned)f2b(src[3 * 64]) << 16);
    pv.z = (unsigned)f2b(src[4 * 64]) | ((unsigned)f2b(src[5 * 64]) << 16);
    pv.w = (unsigned)f2b(src[6 * 64]) | ((unsigned)f2b(src[7 * 64]) << 16);
    *(uint4*)&W2F[(unsigned)((((u * 16 + kg) << 6) + g) << 3)] = pv;
  } else if (blk < 456) {             // A2 row r (fp32 exact)
    int r = blk - 200;
    rowL[tid] = A[r * 256 + tid];
    __syncthreads();
    float acc0 = 0.f, acc1 = 0.f;
    #pragma unroll 8
    for (int k = 0; k < 256; k += 2) {
      acc0 += rowL[k] * A[k * 256 + tid];
      acc1 += rowL[k + 1] * A[(k + 1) * 256 + tid];
    }
    A2[r * 256 + tid] = acc0 + acc1;
  } else if (blk < 488) {             // WBS[u*64+g] = sum_i wb[u][g][i]
    int rowid = (blk - 456) * 4 + (tid >> 6);
    int lane = tid & 63;
    const f32x4* src = (const f32x4*)(wb + (size_t)rowid * 1024);
    float s = 0.f;
    #pragma unroll
    for (int rr = 0; rr < 4; ++rr) {
      f32x4 v = src[lane + 64 * rr];
      s += (v[0] + v[1]) + (v[2] + v[3]);
    }
    #pragma unroll
    for (int m = 1; m < 64; m <<= 1) s += __shfl_xor(s, m);
    if (lane == 0) WBS[rowid] = s;
  } else {                            // BBS[u] = sum_i bb[u][i]
    int wv = tid >> 6, lane = tid & 63;
    if (wv < 2) {
      const f32x4* src = (const f32x4*)(bb + wv * 1024);
      float s = 0.f;
      #pragma unroll
      for (int rr = 0; rr < 4; ++rr) {
        f32x4 v = src[lane + 64 * rr];
        s += (v[0] + v[1]) + (v[2] + v[3]);
      }
      #pragma unroll
      for (int m = 1; m < 64; m <<= 1) s += __shfl_xor(s, m);
      if (lane == 0) BBS[wv] = s;
    }
  }
}

// ---------------------------------------------------------------------------
// K1: fused chain (blocks 0,1) + KAN inner path (blocks 2..257)
// Chain: c_j = A^j c0, parity-2 via A2, quarter-split across waves:
//   thread (q=tid>>6, lane) owns rows {j*64+lane} x column-quarter q of A2 in
//   VGPRs; c-quarter read via uniform-broadcast LDS; partials reduced via
//   conflict-free [q][row] LDS layout. W[127-j] = B_ssm @ c_j accumulated.
// KAN: per 64-row block, x tile in LDS (bf16), L1(K=1024)->relu->L2(K=128)
//   ->relu->gen(K=64,N=1024)+softplus*x, MFMA 16x16x32 bf16; writes INNER.
// ---------------------------------------------------------------------------
__global__ __launch_bounds__(256, 1) void k_fused(
    const float* __restrict__ x, const unsigned short* __restrict__ W1F,
    const unsigned short* __restrict__ W2F, const unsigned short* __restrict__ WWF,
    const float* __restrict__ b1, const float* __restrict__ b2, const float* __restrict__ bwp,
    const float* __restrict__ WBS, const float* __restrict__ BBS, float* __restrict__ INNER,
    const float* __restrict__ A, const float* __restrict__ A2,
    const float* __restrict__ Bs, const float* __restrict__ Cs, float* __restrict__ Wmat)
{
  __shared__ unsigned short XA[64 * 1032];        // kan: x tile bf16 | chain: scratch
  __shared__ unsigned short H1s[4][16 * 136];
  __shared__ unsigned short H2s[4][16 * 72];
  const int tid = threadIdx.x;

  if (blockIdx.x < 2) {
    // ================= chain =================
    float* cbuf = (float*)XA;          // [2][256]
    float* part = cbuf + 512;          // [4][256]  part[q][row]
    float* wp   = part + 1024;         // [64][4][64]
    const int lane = tid & 63, q = tid >> 6;
    const int par = blockIdx.x;

    float bq[64];                      // Bs[m=lane][s = q*64 + 0..63]
    {
      const f32x4* bs = (const f32x4*)(Bs + lane * 256 + q * 64);
      #pragma unroll
      for (int s4 = 0; s4 < 16; ++s4) {
        f32x4 v = bs[s4];
        bq[4 * s4] = v[0]; bq[4 * s4 + 1] = v[1]; bq[4 * s4 + 2] = v[2]; bq[4 * s4 + 3] = v[3];
      }
    }
    float a2q[4][64];                  // A2[j*64+lane][q*64 + s]
    #pragma unroll
    for (int j = 0; j < 4; ++j) {
      const f32x4* a2s = (const f32x4*)(A2 + (size_t)(j * 64 + lane) * 256 + q * 64);
      #pragma unroll
      for (int s4 = 0; s4 < 16; ++s4) {
        f32x4 v = a2s[s4];
        a2q[j][4 * s4] = v[0]; a2q[j][4 * s4 + 1] = v[1];
        a2q[j][4 * s4 + 2] = v[2]; a2q[j][4 * s4 + 3] = v[3];
      }
    }
    if (par == 0) {
      cbuf[tid] = Cs[tid];             // c_0 = C^T
    } else {                           // c_1 = A @ c_0 (one-time full-row dot)
      const f32x4* ar = (const f32x4*)(A + (size_t)tid * 256);
      const f32x4* cs = (const f32x4*)Cs;
      float s0 = 0.f, s1 = 0.f, s2 = 0.f, s3 = 0.f;
      #pragma unroll
      for (int s4 = 0; s4 < 64; ++s4) {
        f32x4 av = ar[s4]; f32x4 cv = cs[s4];
        s0 += av[0] * cv[0]; s1 += av[1] * cv[1]; s2 += av[2] * cv[2]; s3 += av[3] * cv[3];
      }
      cbuf[tid] = (s0 + s1) + (s2 + s3);
    }
    __syncthreads();
    int p = 0;
    for (int it = 0; it < 64; ++it) {
      float cq[64];                    // uniform-broadcast read of my wave's quarter
      {
        const f32x4* cs4 = (const f32x4*)(cbuf + p * 256 + q * 64);
        #pragma unroll
        for (int s4 = 0; s4 < 16; ++s4) {
          f32x4 v = cs4[s4];
          cq[4 * s4] = v[0]; cq[4 * s4 + 1] = v[1]; cq[4 * s4 + 2] = v[2]; cq[4 * s4 + 3] = v[3];
        }
      }
      float wa = 0.f;
      #pragma unroll
      for (int s = 0; s < 64; ++s) wa += bq[s] * cq[s];
      wp[it * 256 + q * 64 + lane] = wa;
      if (it == 63) break;
      float p0 = 0.f, p1 = 0.f, p2 = 0.f, p3 = 0.f;
      #pragma unroll
      for (int s = 0; s < 64; ++s) {
        p0 += a2q[0][s] * cq[s]; p1 += a2q[1][s] * cq[s];
        p2 += a2q[2][s] * cq[s]; p3 += a2q[3][s] * cq[s];
      }
      part[q * 256 + lane]       = p0;
      part[q * 256 + 64 + lane]  = p1;
      part[q * 256 + 128 + lane] = p2;
      part[q * 256 + 192 + lane] = p3;
      __syncthreads();
      cbuf[(p ^ 1) * 256 + tid] =
          (part[tid] + part[256 + tid]) + (part[512 + tid] + part[768 + tid]);
      p ^= 1;
      __syncthreads();
    }
    __syncthreads();
    for (int o = tid; o < 4096; o += 256) {
      int it = o >> 6, m = o & 63;
      int trow = 127 - (par + 2 * it);
      Wmat[trow * 64 + m] =
          (wp[it * 256 + m] + wp[it * 256 + 64 + m]) +
          (wp[it * 256 + 128 + m] + wp[it * 256 + 192 + m]);
    }
    return;
  }

  // ================= KAN =================
  const int wave = tid >> 6, lane = tid & 63, n16 = lane & 15, q = lane >> 4;
  const int row0 = (blockIdx.x - 2) * 64;
  const int srow = tid >> 2, sc4 = tid & 3;
  const float* xrow = x + (size_t)(row0 + srow) * 1024;

  f32x4 pf[8];
  {                                              // stage chunk 0
    const f32x4* s = (const f32x4*)xrow + sc4;
    #pragma unroll
    for (int r = 0; r < 8; ++r) pf[r] = s[4 * r];
    #pragma unroll
    for (int r = 0; r < 8; ++r) {
      uint2 pk;
      pk.x = (unsigned)f2b(pf[r][0]) | ((unsigned)f2b(pf[r][1]) << 16);
      pk.y = (unsigned)f2b(pf[r][2]) | ((unsigned)f2b(pf[r][3]) << 16);
      *(uint2*)&XA[srow * 1032 + (sc4 + 4 * r) * 4] = pk;
    }
  }
  __syncthreads();

  #pragma unroll 1
  for (int u = 0; u < 2; ++u) {
    f32x4 acc[8];
    #pragma unroll
    for (int i = 0; i < 8; ++i) acc[i] = (f32x4){0.f, 0.f, 0.f, 0.f};

    #pragma unroll 1
    for (int kc = 0; kc < 8; ++kc) {
      if (u == 0 && kc < 7) {                    // prefetch next chunk
        const f32x4* s = (const f32x4*)xrow + (kc + 1) * 32 + sc4;
        #pragma unroll
        for (int r = 0; r < 8; ++r) pf[r] = s[4 * r];
      }
      #pragma unroll
      for (int ks = 0; ks < 4; ++ks) {
        bf16x8 af = *(const bf16x8*)&XA[(wave * 16 + n16) * 1032 + kc * 128 + ks * 32 + q * 8];
        #pragma unroll
        for (int nt = 0; nt < 8; ++nt) {
          int kg = kc * 16 + ks * 4 + q;
          bf16x8 bfr = *(const bf16x8*)&W1F[(unsigned)((kg * 256 + u * 128 + nt * 16 + n16) * 8)];
          acc[nt] = __builtin_amdgcn_mfma_f32_16x16x32_bf16(af, bfr, acc[nt], 0, 0, 0);
        }
      }
      if (u == 0 && kc < 7) {                    // commit next chunk to LDS
        #pragma unroll
        for (int r = 0; r < 8; ++r) {
          uint2 pk;
          pk.x = (unsigned)f2b(pf[r][0]) | ((unsigned)f2b(pf[r][1]) << 16);
          pk.y = (unsigned)f2b(pf[r][2]) | ((unsigned)f2b(pf[r][3]) << 16);
          *(uint2*)&XA[srow * 1032 + (kc + 1) * 128 + (sc4 + 4 * r) * 4] = pk;
        }
      }
      if (u == 0) __syncthreads();
    }

    // L1 epilogue: h1 = relu(acc + b1) -> H1s (bf16)
    #pragma unroll
    for (int nt = 0; nt < 8; ++nt) {
      float bias = b1[u * 128 + nt * 16 + n16];
      #pragma unroll
      for (int r = 0; r < 4; ++r) {
        float h = fmaxf(acc[nt][r] + bias, 0.f);
        H1s[wave][(q * 4 + r) * 136 + nt * 16 + n16] = f2b(h);
      }
    }
    // L2: h2 = relu(h1 @ w2 + b2), K=128, N=64
    f32x4 acc2[4];
    #pragma unroll
    for (int i = 0; i < 4; ++i) acc2[i] = (f32x4){0.f, 0.f, 0.f, 0.f};
    #pragma unroll
    for (int ks = 0; ks < 4; ++ks) {
      bf16x8 af = *(const bf16x8*)&H1s[wave][n16 * 136 + ks * 32 + q * 8];
      #pragma unroll
      for (int nt = 0; nt < 4; ++nt) {
        bf16x8 bfr = *(const bf16x8*)&W2F[(unsigned)(((u * 16 + ks * 4 + q) * 64 + nt * 16 + n16) * 8)];
        acc2[nt] = __builtin_amdgcn_mfma_f32_16x16x32_bf16(af, bfr, acc2[nt], 0, 0, 0);
      }
    }
    float bsum[4] = {0.f, 0.f, 0.f, 0.f};
    #pragma unroll
    for (int nt = 0; nt < 4; ++nt) {
      float bias = b2[u * 64 + nt * 16 + n16];
      float wv = WBS[u * 64 + nt * 16 + n16];
      #pragma unroll
      for (int r = 0; r < 4; ++r) {
        float h = fmaxf(acc2[nt][r] + bias, 0.f);
        H2s[wave][(q * 4 + r) * 72 + nt * 16 + n16] = f2b(h);
        bsum[r] += h * wv;
      }
    }
    // gen: z = h2 @ ww + bw ; inner_w = sum_i softplus(z_i) * x_i
    bf16x8 g0 = *(const bf16x8*)&H2s[wave][n16 * 72 + q * 8];
    bf16x8 g1 = *(const bf16x8*)&H2s[wave][n16 * 72 + 32 + q * 8];
    float wsum[4] = {0.f, 0.f, 0.f, 0.f};
    #pragma unroll 4
    for (int nt = 0; nt < 64; ++nt) {
      int i = nt * 16 + n16;
      bf16x8 w0 = *(const bf16x8*)&WWF[(unsigned)(((u * 8 + q) * 1024 + i) * 8)];
      bf16x8 w1v = *(const bf16x8*)&WWF[(unsigned)(((u * 8 + 4 + q) * 1024 + i) * 8)];
      f32x4 z = (f32x4){0.f, 0.f, 0.f, 0.f};
      z = __builtin_amdgcn_mfma_f32_16x16x32_bf16(g0, w0, z, 0, 0, 0);
      z = __builtin_amdgcn_mfma_f32_16x16x32_bf16(g1, w1v, z, 0, 0, 0);
      float bwv = bwp[u * 1024 + i];
      #pragma unroll
      for (int r = 0; r < 4; ++r) {
        float zz = z[r] + bwv;
        float s = softplus_f(zz);
        float xv = b2f(XA[(wave * 16 + q * 4 + r) * 1032 + i]);
        wsum[r] += s * xv;
      }
    }
    #pragma unroll
    for (int r = 0; r < 4; ++r) {
      float v = wsum[r] + bsum[r];
      v += __shfl_xor(v, 1); v += __shfl_xor(v, 2);
      v += __shfl_xor(v, 4); v += __shfl_xor(v, 8);
      if (n16 == 0) INNER[(size_t)(row0 + wave * 16 + q * 4 + r) * 2 + u] = v + BBS[u];
    }
  }
}

// ---------------------------------------------------------------------------
// K2: mamba dot (streaming, HBM-bound, nontemporal) + outer MLP + combine
// ---------------------------------------------------------------------------
__global__ __launch_bounds__(256, 4) void k_mamba(
    const float* __restrict__ xm, const float* __restrict__ Wmat, const float* __restrict__ INNER,
    const float* __restrict__ ow1, const float* __restrict__ ob1,
    const float* __restrict__ ow2, const float* __restrict__ ob2,
    const float* __restrict__ oww, const float* __restrict__ obw,
    const float* __restrict__ owb, const float* __restrict__ obb,
    const float* __restrict__ wkan, const float* __restrict__ wmamba, float* __restrict__ out)
{
  __shared__ float Ws[8192];
  __shared__ float h1o[4][256];
  __shared__ float h2o[4][128];
  const int tid = threadIdx.x, wave = tid >> 6, lane = tid & 63;
  #pragma unroll
  for (int i = 0; i < 8; ++i) ((f32x4*)Ws)[i * 256 + tid] = ((const f32x4*)Wmat)[i * 256 + tid];
  __syncthreads();
  const int row = blockIdx.x * 4 + wave;
  const float* xr = xm + (size_t)row * 8192;
  float a0 = 0.f, a1 = 0.f, a2 = 0.f, a3 = 0.f;
  #pragma unroll 8
  for (int i = 0; i < 32; ++i) {
    f32x4 xv = __builtin_nontemporal_load(&((const f32x4*)xr)[i * 64 + lane]);
    f32x4 wv = ((const f32x4*)Ws)[i * 64 + lane];
    a0 += xv[0] * wv[0]; a1 += xv[1] * wv[1]; a2 += xv[2] * wv[2]; a3 += xv[3] * wv[3];
  }
  float dot = (a0 + a1) + (a2 + a3);
  #pragma unroll
  for (int m = 1; m < 64; m <<= 1) dot += __shfl_xor(dot, m);

  // ---- outer generator (fp32 VALU, hidden under HBM) ----
  float i0 = INNER[(size_t)row * 2], i1 = INNER[(size_t)row * 2 + 1];
  #pragma unroll
  for (int of = 0; of < 4; ++of) {
    int idx = of * 64 + lane;
    int o = idx >> 7, f = idx & 127;
    float h = fmaxf(i0 * ow1[o * 256 + f] + i1 * ow1[o * 256 + 128 + f] + ob1[idx], 0.f);
    h1o[wave][idx] = h;
  }
  __syncthreads();
  #pragma unroll
  for (int oh = 0; oh < 2; ++oh) {
    float acc = ob2[oh * 64 + lane];
    #pragma unroll 8
    for (int f = 0; f < 128; ++f)
      acc += h1o[wave][oh * 128 + f] * ow2[(oh * 128 + f) * 64 + lane];
    h2o[wave][oh * 64 + lane] = fmaxf(acc, 0.f);
  }
  __syncthreads();
  float p0 = h2o[wave][lane] * oww[lane];
  float p1 = h2o[wave][64 + lane] * oww[64 + lane];
  float pb0 = h2o[wave][lane] * owb[lane];
  float pb1 = h2o[wave][64 + lane] * owb[64 + lane];
  #pragma unroll
  for (int m = 1; m < 64; m <<= 1) {
    p0 += __shfl_xor(p0, m); p1 += __shfl_xor(p1, m);
    pb0 += __shfl_xor(pb0, m); pb1 += __shfl_xor(pb1, m);
  }
  float w0 = softplus_f(p0 + obw[0]), w1 = softplus_f(p1 + obw[1]);
  float b0 = pb0 + obb[0], b1v = pb1 + obb[1];
  float isum = i0 + i1;
  float kan = w0 * isum + 2.f * b0 + w1 * isum + 2.f * b1v;
  if (lane == 0) out[row] = wkan[0] * kan + wmamba[0] * dot;
}

// ---------------------------------------------------------------------------
extern "C" void kernel_launch(void* const* d_in, const int* in_sizes, int n_in,
                              void* d_out, int out_size, void* d_ws, size_t ws_size,
                              hipStream_t stream) {
  (void)in_sizes; (void)n_in; (void)out_size; (void)ws_size;
  const float* x_kan   = (const float*)d_in[0];
  const float* x_mamba = (const float*)d_in[1];
  const float* in_w1 = (const float*)d_in[2];
  const float* in_b1 = (const float*)d_in[3];
  const float* in_w2 = (const float*)d_in[4];
  const float* in_b2 = (const float*)d_in[5];
  const float* in_ww = (const float*)d_in[6];
  const float* in_bw = (const float*)d_in[7];
  const float* in_wb = (const float*)d_in[8];
  const float* in_bb = (const float*)d_in[9];
  const float* out_w1 = (const float*)d_in[10];
  const float* out_b1 = (const float*)d_in[11];
  const float* out_w2 = (const float*)d_in[12];
  const float* out_b2 = (const float*)d_in[13];
  const float* out_ww = (const float*)d_in[14];
  const float* out_bw = (const float*)d_in[15];
  const float* out_wb = (const float*)d_in[16];
  const float* out_bb = (const float*)d_in[17];
  const float* A  = (const float*)d_in[18];
  const float* Bs = (const float*)d_in[19];
  const float* Cs = (const float*)d_in[20];
  const float* wkan   = (const float*)d_in[21];
  const float* wmamba = (const float*)d_in[22];
  float* out = (float*)d_out;

  char* ws = (char*)d_ws;
  unsigned short* W1F = (unsigned short*)(ws + 0);         // 512 KB
  unsigned short* WWF = (unsigned short*)(ws + 524288);    // 256 KB
  unsigned short* W2F = (unsigned short*)(ws + 786432);    // 32 KB
  float* A2    = (float*)(ws + 819200);                    // 256 KB
  float* WBS   = (float*)(ws + 1081344);                   // 512 B
  float* BBS   = (float*)(ws + 1082368);                   // 8 B
  float* WMAT  = (float*)(ws + 1082624);                   // 32 KB
  float* INNER = (float*)(ws + 1115392);                   // 128 KB

  k_prep<<<489, 256, 0, stream>>>(in_w1, in_w2, in_ww, in_wb, in_bb, A,
                                  W1F, W2F, WWF, A2, WBS, BBS);
  k_fused<<<258, 256, 0, stream>>>(x_kan, W1F, W2F, WWF, in_b1, in_b2, in_bw,
                                   WBS, BBS, INNER, A, A2, Bs, Cs, WMAT);
  k_mamba<<<4096, 256, 0, stream>>>(x_mamba, WMAT, INNER, out_w1, out_b1, out_w2, out_b2,
                                    out_ww, out_bw, out_wb, out_bb, wkan, wmamba, out);
}